// Round 1
// 145.898 us; speedup vs baseline: 1.0728x; 1.0728x over previous
//
#include <hip/hip_runtime.h>

#define N_NODES 50000
#define N_EDGES 800000
#define IN_DIM 128
#define OUT_DIM 64
#define CAP 64            // max row degree ~35 (Binomial(800k,1/50k)), 64 is safe
#define PARTS 8           // row partitions == XCD count
#define ROWS_PER_PART 6250
#define EDGES_PER_CHUNK 3125   // 800000 / 256 chunks
#define BUCKET_BLOCKS (256 * PARTS)   // 2048
#define GEMM_BLOCKS 782               // ceil(3125 groups / 4 waves)

// workspace layout (bytes), 16B-aligned
#define OFF_HID 0u          // bf16 hidden: 50000*64*2 = 6,400,000
#define OFF_DEG 6400000u    // int deg: 200,000
#define OFF_BKT 6600192u    // int2 bucket: 50000*64*8 = 25,600,000  (total ~32 MB)

typedef short short8 __attribute__((ext_vector_type(8)));
typedef float f32x4 __attribute__((ext_vector_type(4)));

__device__ __forceinline__ unsigned short bf_rne(float f) {
    unsigned u = __float_as_uint(f);
    u += 0x7fffu + ((u >> 16) & 1u);   // round-to-nearest-even
    return (unsigned short)(u >> 16);
}
__device__ __forceinline__ float bf_lo(unsigned u) { return __uint_as_float(u << 16); }
__device__ __forceinline__ float bf_hi(unsigned u) { return __uint_as_float(u & 0xffff0000u); }

// ---------------------------------------------------------------------------
// FUSED kernel: blocks [0, 2048) do edge bucketing (XCD-partitioned, same
// part = blockIdx&7 mapping as before since bucket blocks keep the low
// indices); blocks [2048, 2048+782) do the MFMA GEMM. The two phases are
// data-independent, so fusing overlaps the bucket's atomic/VMEM latency with
// the GEMM's MFMA work instead of serializing them on the stream.
// ---------------------------------------------------------------------------
__global__ __launch_bounds__(256) void fused_kernel(
        const float* __restrict__ x, const float* __restrict__ w,
        unsigned short* __restrict__ hidb,
        const int* __restrict__ erow, const int* __restrict__ ecol,
        const float* __restrict__ eval,
        int* __restrict__ deg, int2* __restrict__ bucket) {
    if (blockIdx.x < BUCKET_BLOCKS) {
        // ---- bucket path (no LDS, no barriers) ----
        const int part = blockIdx.x & (PARTS - 1);
        const int chunk = blockIdx.x >> 3;
        const int rlo = part * ROWS_PER_PART;
        const int e0 = chunk * EDGES_PER_CHUNK;
        for (int i = threadIdx.x; i < EDGES_PER_CHUNK; i += 256) {
            const int e = e0 + i;
            const int r = erow[e];
            const int c = ecol[e];     // always-load: line is ~88% fetched anyway
            const float v = eval[e];
            if ((unsigned)(r - rlo) < (unsigned)ROWS_PER_PART) {
                const int pos = atomicAdd(&deg[r], 1);
                if (pos < CAP) bucket[(size_t)r * CAP + pos] = make_int2(c, __float_as_int(v));
            }
        }
        return;
    }

    // ---- GEMM path: hidden(bf16) = x @ w, one wave per 16-node group ----
    // smem double-duty: first holds the permuted B-fragments (16 KB), then is
    // reused as the per-wave epilogue bounce buffer (frags are snapshotted to
    // registers, second __syncthreads fences the reuse).
    __shared__ __attribute__((aligned(16))) unsigned short smem[16 * 64 * 8];  // 16 KB

    const int tid = threadIdx.x;
    const int lane = tid & 63;
    const int wid = tid >> 6;

    // stage w into B-fragment order
    for (int s = tid; s < 16 * 64 * 8; s += 256) {
        const int f = s >> 9;
        const int ln = (s >> 3) & 63;
        const int j = s & 7;
        const int c = f >> 2, t = f & 3;
        const int k = c * 32 + (ln >> 4) * 8 + j;
        const int n = t * 16 + (ln & 15);
        smem[s] = bf_rne(w[k * OUT_DIM + n]);
    }
    __syncthreads();

    const int group = (blockIdx.x - BUCKET_BLOCKS) * 4 + wid;   // 16-node group id
    const bool act = group < N_NODES / 16;

    short8 bf[16];
    if (act) {
        #pragma unroll
        for (int f = 0; f < 16; ++f)
            bf[f] = *(const short8*)&smem[(f * 64 + lane) * 8];
    }
    __syncthreads();   // all waves have their frags in regs -> smem reusable

    if (act) {
        const int node0 = group * 16;
        f32x4 acc[4] = {{0, 0, 0, 0}, {0, 0, 0, 0}, {0, 0, 0, 0}, {0, 0, 0, 0}};

        #pragma unroll
        for (int c = 0; c < 4; ++c) {
            const float* xr = x + (size_t)(node0 + (lane & 15)) * IN_DIM + c * 32 + (lane >> 4) * 8;
            const float4 a0 = *(const float4*)xr;
            const float4 a1 = *(const float4*)(xr + 4);
            short8 af;
            af[0] = (short)bf_rne(a0.x); af[1] = (short)bf_rne(a0.y);
            af[2] = (short)bf_rne(a0.z); af[3] = (short)bf_rne(a0.w);
            af[4] = (short)bf_rne(a1.x); af[5] = (short)bf_rne(a1.y);
            af[6] = (short)bf_rne(a1.z); af[7] = (short)bf_rne(a1.w);
            #pragma unroll
            for (int t = 0; t < 4; ++t)
                acc[t] = __builtin_amdgcn_mfma_f32_16x16x32_bf16(af, bf[c * 4 + t], acc[t], 0, 0, 0);
        }

        // epilogue: D[m][n] -> smem bounce (wave-private 1024-short slice) -> global
        unsigned short* obuf = smem + wid * 1024;
        #pragma unroll
        for (int t = 0; t < 4; ++t)
            #pragma unroll
            for (int r = 0; r < 4; ++r)
                obuf[((lane >> 4) * 4 + r) * 64 + t * 16 + (lane & 15)] = bf_rne(acc[t][r]);
        // wave-private region: intra-wave lgkmcnt ordering suffices, no barrier
        const uint4 o0 = *(const uint4*)&obuf[lane * 16];
        const uint4 o1 = *(const uint4*)&obuf[lane * 16 + 8];
        char* dst = (char*)hidb + (size_t)node0 * (OUT_DIM * 2) + lane * 32;
        *(uint4*)dst = o0;
        *(uint4*)(dst + 16) = o1;
    }
}

// ---------------------------------------------------------------------------
// Aggregate, MLP-restructured: 4 rows per wave (quarter q = row, 16 lanes
// cover the full 128 B hidden row with 8 B each -> 512 B per gather instr).
// Edge (col,val) pairs are staged to registers once (ep[l], ep[16+l]) and
// broadcast per-edge via __shfl, removing the per-iteration bucket-load ->
// gather serial dependency. Gathers batched 8-deep into a register array
// before any fma so 8 independent loads are in flight. Inactive edge slots
// are clamped (c=0, v=0) -> branch-free, no OOB.
// ---------------------------------------------------------------------------
__device__ __forceinline__ void proc8(const unsigned short* __restrict__ hidb,
                                      int2 P, int base, int eoff,
                                      int q, int l, int d, float4& acc) {
    unsigned long long u[8];
    float vv[8];
    #pragma unroll
    for (int e = 0; e < 8; ++e) {
        const int src = q * 16 + eoff + e;
        int c = __shfl(P.x, src);
        const int vi = __shfl(P.y, src);
        const bool act = (base + eoff + e) < d;
        c = act ? c : 0;
        vv[e] = act ? __int_as_float(vi) : 0.f;
        u[e] = *(const unsigned long long*)&hidb[(size_t)c * OUT_DIM + 4 * l];
    }
    #pragma unroll
    for (int e = 0; e < 8; ++e) {
        const float v = vv[e];
        const unsigned ulo = (unsigned)u[e];
        const unsigned uhi = (unsigned)(u[e] >> 32);
        acc.x = fmaf(v, bf_lo(ulo), acc.x);
        acc.y = fmaf(v, bf_hi(ulo), acc.y);
        acc.z = fmaf(v, bf_lo(uhi), acc.z);
        acc.w = fmaf(v, bf_hi(uhi), acc.w);
    }
}

__global__ __launch_bounds__(256) void agg_kernel(const unsigned short* __restrict__ hidb,
                                                  const int* __restrict__ deg,
                                                  const int2* __restrict__ bucket,
                                                  const float* __restrict__ b,
                                                  float* __restrict__ out) {
    const int tid = threadIdx.x;
    const int lane = tid & 63;
    const int wid = tid >> 6;
    const int q = lane >> 4;        // quarter = which of the wave's 4 rows
    const int l = lane & 15;        // dims 4l .. 4l+3
    const int row = blockIdx.x * 16 + wid * 4 + q;   // grid covers exactly 50000

    const int d = min(deg[row], CAP);
    const int2* __restrict__ ep = bucket + (size_t)row * CAP;

    // wave-uniform max degree over the 4 quarters (uniform loop trip counts)
    int dmax = d;
    dmax = max(dmax, __shfl_xor(dmax, 16));
    dmax = max(dmax, __shfl_xor(dmax, 32));

    // stage first 32 edge slots to registers (covers P(deg>32) ~ 1e-4 rows;
    // beyond-deg entries are poison but gated off via act-clamp)
    const int2 pa = ep[l];
    const int2 pb = ep[16 + l];

    float4 acc = make_float4(0.f, 0.f, 0.f, 0.f);

    proc8(hidb, pa, 0, 0, q, l, d, acc);
    if (dmax > 8)  proc8(hidb, pa, 0, 8, q, l, d, acc);
    if (dmax > 16) proc8(hidb, pb, 16, 0, q, l, d, acc);
    if (dmax > 24) proc8(hidb, pb, 16, 8, q, l, d, acc);
    for (int base = 32; base < dmax; base += 16) {     // rare tail
        const int2 pc = ep[base + l];
        proc8(hidb, pc, base, 0, q, l, d, acc);
        if (dmax > base + 8) proc8(hidb, pc, base, 8, q, l, d, acc);
    }

    const float4 bb = *(const float4*)&b[4 * l];
    float4 o;
    o.x = fmaxf(acc.x + bb.x, 0.f);
    o.y = fmaxf(acc.y + bb.y, 0.f);
    o.z = fmaxf(acc.z + bb.z, 0.f);
    o.w = fmaxf(acc.w + bb.w, 0.f);
    *(float4*)&out[(size_t)row * OUT_DIM + 4 * l] = o;
}

extern "C" void kernel_launch(void* const* d_in, const int* in_sizes, int n_in,
                              void* d_out, int out_size, void* d_ws, size_t ws_size,
                              hipStream_t stream) {
    const float* x    = (const float*)d_in[0];
    const int*   erow = (const int*)d_in[1];
    const int*   ecol = (const int*)d_in[2];
    const float* eval = (const float*)d_in[3];
    const float* w    = (const float*)d_in[4];
    const float* b    = (const float*)d_in[5];
    float* out = (float*)d_out;

    char* ws = (char*)d_ws;
    unsigned short* hidb = (unsigned short*)(ws + OFF_HID);
    int*  deg    = (int*)(ws + OFF_DEG);
    int2* bucket = (int2*)(ws + OFF_BKT);

    hipMemsetAsync(deg, 0, N_NODES * sizeof(int), stream);

    // 1) fused: bucket (blocks 0..2047, XCD-partitioned) + GEMM (blocks 2048..2829)
    fused_kernel<<<BUCKET_BLOCKS + GEMM_BLOCKS, 256, 0, stream>>>(
        x, w, hidb, erow, ecol, eval, deg, bucket);

    // 2) per-row gather-accumulate (4 rows/wave), fused bias+relu
    agg_kernel<<<N_NODES / 16, 256, 0, stream>>>(hidb, deg, bucket, b, out);
}

// Round 2
// 140.187 us; speedup vs baseline: 1.1165x; 1.0407x over previous
//
#include <hip/hip_runtime.h>

#define N_NODES 50000
#define N_EDGES 800000
#define IN_DIM 128
#define OUT_DIM 64
#define CAP 64            // max row degree ~35 (Binomial(800k,1/50k)), 64 is safe
#define PARTS 8           // row partitions == XCD count
#define ROWS_PER_PART 6250
#define EDGES_PER_CHUNK 3125   // 800000 / 256 chunks

// Block layout: GEMM blocks FIRST so they are co-resident with the bucket
// blocks (8 blocks/CU * 256 CU = 2048 resident; bucket-first put all 2048
// bucket blocks on the machine before any GEMM block -> zero overlap).
#define GEMM_BLOCKS 784               // 784*4 waves = 3136 >= 3125 groups; 784%8==0
#define BUCKET_BLOCKS (256 * PARTS)   // 2048
#define TOTAL_BLOCKS (GEMM_BLOCKS + BUCKET_BLOCKS)

// workspace layout (bytes), 16B-aligned
#define OFF_HID 0u          // bf16 hidden: 50000*64*2 = 6,400,000
#define OFF_DEG 6400000u    // int deg: 200,000
#define OFF_BKT 6600192u    // int2 bucket: 50000*64*8 = 25,600,000  (total ~32 MB)

typedef short short8 __attribute__((ext_vector_type(8)));
typedef float f32x4 __attribute__((ext_vector_type(4)));

__device__ __forceinline__ unsigned short bf_rne(float f) {
    unsigned u = __float_as_uint(f);
    u += 0x7fffu + ((u >> 16) & 1u);   // round-to-nearest-even
    return (unsigned short)(u >> 16);
}
__device__ __forceinline__ float bf_lo(unsigned u) { return __uint_as_float(u << 16); }
__device__ __forceinline__ float bf_hi(unsigned u) { return __uint_as_float(u & 0xffff0000u); }

// ---------------------------------------------------------------------------
// FUSED kernel. blocks [0, 784): MFMA GEMM hidden = x @ w. blocks [784, 2832):
// edge bucketing, XCD-partitioned (part = blockIdx&7 == XCD since base%8==0).
// ---------------------------------------------------------------------------
__global__ __launch_bounds__(256) void fused_kernel(
        const float* __restrict__ x, const float* __restrict__ w,
        unsigned short* __restrict__ hidb,
        const int* __restrict__ erow, const int* __restrict__ ecol,
        const float* __restrict__ eval,
        int* __restrict__ deg, int2* __restrict__ bucket) {
    if (blockIdx.x >= GEMM_BLOCKS) {
        // ---- bucket path (no LDS, no barriers) ----
        const int bb = blockIdx.x - GEMM_BLOCKS;
        const int part = bb & (PARTS - 1);           // == blockIdx%8 == XCD
        const int chunk = bb >> 3;
        const int rlo = part * ROWS_PER_PART;
        const int e0 = chunk * EDGES_PER_CHUNK;
        // 2x manual unroll: two independent atomic chains in flight
        int i = threadIdx.x;
        for (; i + 256 < EDGES_PER_CHUNK; i += 512) {
            const int eA = e0 + i, eB = e0 + i + 256;
            const int rA = erow[eA], rB = erow[eB];
            const int cA = ecol[eA], cB = ecol[eB];
            const float vA = eval[eA], vB = eval[eB];
            if ((unsigned)(rA - rlo) < (unsigned)ROWS_PER_PART) {
                const int pos = atomicAdd(&deg[rA], 1);
                if (pos < CAP) bucket[(size_t)rA * CAP + pos] = make_int2(cA, __float_as_int(vA));
            }
            if ((unsigned)(rB - rlo) < (unsigned)ROWS_PER_PART) {
                const int pos = atomicAdd(&deg[rB], 1);
                if (pos < CAP) bucket[(size_t)rB * CAP + pos] = make_int2(cB, __float_as_int(vB));
            }
        }
        if (i < EDGES_PER_CHUNK) {
            const int e = e0 + i;
            const int r = erow[e];
            const int c = ecol[e];
            const float v = eval[e];
            if ((unsigned)(r - rlo) < (unsigned)ROWS_PER_PART) {
                const int pos = atomicAdd(&deg[r], 1);
                if (pos < CAP) bucket[(size_t)r * CAP + pos] = make_int2(c, __float_as_int(v));
            }
        }
        return;
    }

    // ---- GEMM path: hidden(bf16) = x @ w, one wave per 16-node group ----
    // smem double-duty: permuted B-fragments (16 KB), then epilogue bounce.
    __shared__ __attribute__((aligned(16))) unsigned short smem[16 * 64 * 8];  // 16 KB

    const int tid = threadIdx.x;
    const int lane = tid & 63;
    const int wid = tid >> 6;

    // stage w into B-fragment order — COALESCED global reads (float4 linear
    // over w), scattered cheap LDS u16 writes. Mapping (verified):
    //   e = k*64+n ; c=k>>5, j=k&7, t=n>>4, ln=((k>>3)&3)*16+(n&15)
    //   wperm[((c*4+t)*64+ln)*8+j] = bf16(w[e])
    #pragma unroll
    for (int it = 0; it < 8; ++it) {
        const int e = it * 1024 + tid * 4;
        const float4 wv = *(const float4*)(w + e);
        const int k = e >> 6;
        const int n0 = e & 63;
        const int c = k >> 5, j = k & 7, lhi = ((k >> 3) & 3) * 16;
        #pragma unroll
        for (int m = 0; m < 4; ++m) {
            const int n = n0 + m;
            const int t = n >> 4;
            const int ln = lhi + (n & 15);
            const float fv = (m == 0) ? wv.x : (m == 1) ? wv.y : (m == 2) ? wv.z : wv.w;
            smem[((c * 4 + t) * 64 + ln) * 8 + j] = bf_rne(fv);
        }
    }
    __syncthreads();

    const int group = blockIdx.x * 4 + wid;   // 16-node group id
    const bool act = group < (N_NODES / 16 + 1);   // 3125 groups exactly; guard below

    short8 bf[16];
    if (group < N_NODES / 16) {
        #pragma unroll
        for (int f = 0; f < 16; ++f)
            bf[f] = *(const short8*)&smem[(f * 64 + lane) * 8];
    }
    __syncthreads();   // all waves have their frags in regs -> smem reusable
    (void)act;

    if (group < N_NODES / 16) {
        const int node0 = group * 16;
        f32x4 acc[4] = {{0, 0, 0, 0}, {0, 0, 0, 0}, {0, 0, 0, 0}, {0, 0, 0, 0}};

        #pragma unroll
        for (int c = 0; c < 4; ++c) {
            const float* xr = x + (size_t)(node0 + (lane & 15)) * IN_DIM + c * 32 + (lane >> 4) * 8;
            const float4 a0 = *(const float4*)xr;
            const float4 a1 = *(const float4*)(xr + 4);
            short8 af;
            af[0] = (short)bf_rne(a0.x); af[1] = (short)bf_rne(a0.y);
            af[2] = (short)bf_rne(a0.z); af[3] = (short)bf_rne(a0.w);
            af[4] = (short)bf_rne(a1.x); af[5] = (short)bf_rne(a1.y);
            af[6] = (short)bf_rne(a1.z); af[7] = (short)bf_rne(a1.w);
            #pragma unroll
            for (int t = 0; t < 4; ++t)
                acc[t] = __builtin_amdgcn_mfma_f32_16x16x32_bf16(af, bf[c * 4 + t], acc[t], 0, 0, 0);
        }

        // epilogue: D[m][n] -> smem bounce (wave-private 1024-short slice) -> global
        unsigned short* obuf = smem + wid * 1024;
        #pragma unroll
        for (int t = 0; t < 4; ++t)
            #pragma unroll
            for (int r = 0; r < 4; ++r)
                obuf[((lane >> 4) * 4 + r) * 64 + t * 16 + (lane & 15)] = bf_rne(acc[t][r]);
        // wave-private region: intra-wave lgkmcnt ordering suffices, no barrier
        const uint4 o0 = *(const uint4*)&obuf[lane * 16];
        const uint4 o1 = *(const uint4*)&obuf[lane * 16 + 8];
        char* dst = (char*)hidb + (size_t)node0 * (OUT_DIM * 2) + lane * 32;
        *(uint4*)dst = o0;
        *(uint4*)(dst + 16) = o1;
    }
}

// ---------------------------------------------------------------------------
// Aggregate: 4 rows per wave (quarter q = row, 16 lanes cover the full 128 B
// hidden row, 8 B each -> 512 B per gather instr). Edge (col,val) staged to
// registers once, broadcast via __shfl; gathers batched 8-deep before fmas.
// ---------------------------------------------------------------------------
__device__ __forceinline__ void proc8(const unsigned short* __restrict__ hidb,
                                      int2 P, int base, int eoff,
                                      int q, int l, int d, float4& acc) {
    unsigned long long u[8];
    float vv[8];
    #pragma unroll
    for (int e = 0; e < 8; ++e) {
        const int src = q * 16 + eoff + e;
        int c = __shfl(P.x, src);
        const int vi = __shfl(P.y, src);
        const bool act = (base + eoff + e) < d;
        c = act ? c : 0;
        vv[e] = act ? __int_as_float(vi) : 0.f;
        u[e] = *(const unsigned long long*)&hidb[(size_t)c * OUT_DIM + 4 * l];
    }
    #pragma unroll
    for (int e = 0; e < 8; ++e) {
        const float v = vv[e];
        const unsigned ulo = (unsigned)u[e];
        const unsigned uhi = (unsigned)(u[e] >> 32);
        acc.x = fmaf(v, bf_lo(ulo), acc.x);
        acc.y = fmaf(v, bf_hi(ulo), acc.y);
        acc.z = fmaf(v, bf_lo(uhi), acc.z);
        acc.w = fmaf(v, bf_hi(uhi), acc.w);
    }
}

__global__ __launch_bounds__(256) void agg_kernel(const unsigned short* __restrict__ hidb,
                                                  const int* __restrict__ deg,
                                                  const int2* __restrict__ bucket,
                                                  const float* __restrict__ b,
                                                  float* __restrict__ out) {
    const int tid = threadIdx.x;
    const int lane = tid & 63;
    const int wid = tid >> 6;
    const int q = lane >> 4;        // quarter = which of the wave's 4 rows
    const int l = lane & 15;        // dims 4l .. 4l+3
    const int row = blockIdx.x * 16 + wid * 4 + q;   // grid covers exactly 50000

    const int d = min(deg[row], CAP);
    const int2* __restrict__ ep = bucket + (size_t)row * CAP;

    // wave-uniform max degree over the 4 quarters (uniform loop trip counts)
    int dmax = d;
    dmax = max(dmax, __shfl_xor(dmax, 16));
    dmax = max(dmax, __shfl_xor(dmax, 32));

    // stage first 32 edge slots to registers; beyond-deg entries gated off
    const int2 pa = ep[l];
    const int2 pb = ep[16 + l];

    float4 acc = make_float4(0.f, 0.f, 0.f, 0.f);

    proc8(hidb, pa, 0, 0, q, l, d, acc);
    if (dmax > 8)  proc8(hidb, pa, 0, 8, q, l, d, acc);
    if (dmax > 16) proc8(hidb, pb, 16, 0, q, l, d, acc);
    if (dmax > 24) proc8(hidb, pb, 16, 8, q, l, d, acc);
    for (int base = 32; base < dmax; base += 16) {     // rare tail
        const int2 pc = ep[base + l];
        proc8(hidb, pc, base, 0, q, l, d, acc);
        if (dmax > base + 8) proc8(hidb, pc, base, 8, q, l, d, acc);
    }

    const float4 bb = *(const float4*)&b[4 * l];
    float4 o;
    o.x = fmaxf(acc.x + bb.x, 0.f);
    o.y = fmaxf(acc.y + bb.y, 0.f);
    o.z = fmaxf(acc.z + bb.z, 0.f);
    o.w = fmaxf(acc.w + bb.w, 0.f);
    *(float4*)&out[(size_t)row * OUT_DIM + 4 * l] = o;
}

extern "C" void kernel_launch(void* const* d_in, const int* in_sizes, int n_in,
                              void* d_out, int out_size, void* d_ws, size_t ws_size,
                              hipStream_t stream) {
    const float* x    = (const float*)d_in[0];
    const int*   erow = (const int*)d_in[1];
    const int*   ecol = (const int*)d_in[2];
    const float* eval = (const float*)d_in[3];
    const float* w    = (const float*)d_in[4];
    const float* b    = (const float*)d_in[5];
    float* out = (float*)d_out;

    char* ws = (char*)d_ws;
    unsigned short* hidb = (unsigned short*)(ws + OFF_HID);
    int*  deg    = (int*)(ws + OFF_DEG);
    int2* bucket = (int2*)(ws + OFF_BKT);

    hipMemsetAsync(deg, 0, N_NODES * sizeof(int), stream);

    // 1) fused: GEMM (blocks 0..783) overlapped with bucket (blocks 784..2831)
    fused_kernel<<<TOTAL_BLOCKS, 256, 0, stream>>>(
        x, w, hidb, erow, ecol, eval, deg, bucket);

    // 2) per-row gather-accumulate (4 rows/wave), fused bias+relu
    agg_kernel<<<N_NODES / 16, 256, 0, stream>>>(hidb, deg, bucket, b, out);
}